// Round 1
// baseline (84.852 us; speedup 1.0000x reference)
//
#include <hip/hip_runtime.h>
#include <cstddef>

constexpr int B_  = 16;
constexpr int K_  = 5;
constexpr int C_  = 256;
constexpr int HW_ = 128 * 128;
constexpr int Q_  = 64;

// ---------------------------------------------------------------------------
// Kernel 1: per-pixel prediction.
// pred[b,p] = gt[b,p] if b < label_bs else argmax_k res1[b,k,p] (first max).
// ---------------------------------------------------------------------------
__global__ __launch_bounds__(256) void pred_kernel(
    const float* __restrict__ res1, const int* __restrict__ gt,
    const int* __restrict__ label_bs, int* __restrict__ pred)
{
    int idx = blockIdx.x * 256 + threadIdx.x;   // 0 .. B*HW
    int b = idx >> 14;                          // / HW_
    int p = idx & (HW_ - 1);
    int lb = label_bs[0];
    int pr;
    if (b < lb) {
        pr = gt[idx];
    } else {
        const float* r = res1 + (size_t)b * K_ * HW_ + p;
        float best = r[0];
        pr = 0;
        #pragma unroll
        for (int k = 1; k < K_; ++k) {
            float v = r[(size_t)k * HW_];
            if (v > best) { best = v; pr = k; }   // strict >: first-max, matches jnp.argmax
        }
    }
    pred[idx] = pr;
}

// ---------------------------------------------------------------------------
// Kernel 2: masked segment sums. One block per (b,c). Block streams the whole
// HW row; per-thread branchless class partials; block reduce; direct write of
// sums[b,k,c] (unique owner -> no atomics). c==0 block also writes counts.
// ---------------------------------------------------------------------------
__global__ __launch_bounds__(256) void segsum_kernel(
    const float* __restrict__ fea, const int* __restrict__ pred,
    float* __restrict__ sums, float* __restrict__ counts)
{
    int bc = blockIdx.x;
    int b = bc >> 8;              // / C_
    int c = bc & (C_ - 1);
    int tid = threadIdx.x;
    const float4* frow = reinterpret_cast<const float4*>(fea + ((size_t)b * C_ + c) * HW_);
    const int4*   prow = reinterpret_cast<const int4*>(pred + (size_t)b * HW_);

    float acc[K_] = {};
    int   cnt[K_] = {};
    const bool do_count = (c == 0);

    for (int i = tid; i < HW_ / 4; i += 256) {
        float4 v = frow[i];
        int4   pk = prow[i];
        #pragma unroll
        for (int k = 0; k < K_; ++k) {
            acc[k] += (pk.x == k ? v.x : 0.f)
                    + (pk.y == k ? v.y : 0.f)
                    + (pk.z == k ? v.z : 0.f)
                    + (pk.w == k ? v.w : 0.f);
        }
        if (do_count) {
            #pragma unroll
            for (int k = 0; k < K_; ++k) {
                cnt[k] += (pk.x == k) + (pk.y == k) + (pk.z == k) + (pk.w == k);
            }
        }
    }

    __shared__ float red[4][K_];
    __shared__ int   redc[4][K_];
    int lane = tid & 63, wv = tid >> 6;
    #pragma unroll
    for (int k = 0; k < K_; ++k) {
        float v = acc[k];
        #pragma unroll
        for (int off = 32; off > 0; off >>= 1) v += __shfl_down(v, off);
        if (lane == 0) red[wv][k] = v;
        if (do_count) {
            int ci = cnt[k];
            #pragma unroll
            for (int off = 32; off > 0; off >>= 1) ci += __shfl_down(ci, off);
            if (lane == 0) redc[wv][k] = ci;
        }
    }
    __syncthreads();
    if (tid < K_) {
        float s = red[0][tid] + red[1][tid] + red[2][tid] + red[3][tid];
        sums[((size_t)b * K_ + tid) * C_ + c] = s;
        if (do_count) {
            counts[b * K_ + tid] =
                (float)(redc[0][tid] + redc[1][tid] + redc[2][tid] + redc[3][tid]);
        }
    }
}

// ---------------------------------------------------------------------------
// Kernel 3: per-sample contrastive tail. One block (256 thr = 4 waves) per b.
// ---------------------------------------------------------------------------
__global__ __launch_bounds__(256) void loss_kernel(
    const float* __restrict__ sums, const float* __restrict__ counts,
    const float* __restrict__ queues, float* __restrict__ per_sample)
{
    int b = blockIdx.x;
    int tid = threadIdx.x;
    int lane = tid & 63, wv = tid >> 6;

    __shared__ float keys[K_][C_];     // normalized means
    __shared__ float cnt_s[K_];
    __shared__ float wred[4];
    __shared__ int   prev_s[K_];
    __shared__ int   valid_s[K_];
    __shared__ int   denom_s;
    __shared__ float sumE_s[K_][K_];
    __shared__ float lpos_s[K_][Q_];
    __shared__ float logprob_s[K_];

    // means (C_ == blockDim: thread tid owns channel tid)
    #pragma unroll
    for (int k = 0; k < K_; ++k) {
        float cv = counts[b * K_ + k];
        keys[k][tid] = sums[((size_t)b * K_ + k) * C_ + tid] / fmaxf(cv, 1.0f);
    }
    if (tid < K_) cnt_s[tid] = counts[b * K_ + tid];
    __syncthreads();

    // L2 normalize each class mean over C
    for (int k = 0; k < K_; ++k) {
        float v = keys[k][tid];
        float s = v * v;
        #pragma unroll
        for (int off = 32; off > 0; off >>= 1) s += __shfl_down(s, off);
        if (lane == 0) wred[wv] = s;
        __syncthreads();
        float nrm = sqrtf(wred[0] + wred[1] + wred[2] + wred[3]);
        keys[k][tid] = v / fmaxf(nrm, 1e-12f);
        __syncthreads();   // protect wred before next iteration rewrites it
    }

    // present / prev (cummax off-by-one) / valid / denom — replicate reference
    if (tid == 0) {
        int last = -1, smallest = -1, npres = 0;
        #pragma unroll
        for (int k = 0; k < K_; ++k) {
            bool pres = cnt_s[k] > 0.0f;
            prev_s[k] = last;
            // valid = present & (k != smallest) & (prev >= 0)
            valid_s[k] = (pres && smallest >= 0 && last >= 0) ? 1 : 0;
            if (pres && smallest < 0) smallest = k;
            if (pres) { ++npres; last = k; }
        }
        denom_s = npres - 1;
    }
    __syncthreads();

    // sim[b,k,j,q] and l_pos[b,k,q]; wave handles (k,j) pairs, lanes = q
    for (int pair = wv; pair < K_ * K_; pair += 4) {
        int k = pair / K_;
        int j = pair - k * K_;
        int pk = prev_s[k] < 0 ? 0 : prev_s[k];   // query = keys[max(prev,0)]
        const float* qj = queues + (size_t)j * C_ * Q_ + lane;
        float acc = 0.f;
        for (int c = 0; c < C_; ++c)
            acc += keys[pk][c] * qj[(size_t)c * Q_];
        acc = acc / 0.2f;                          // / T
        float e = expf(acc);
        float se = e;
        #pragma unroll
        for (int off = 32; off > 0; off >>= 1) se += __shfl_down(se, off);
        if (lane == 0) sumE_s[k][j] = se;
        if (j == k) lpos_s[k][lane] = acc;
    }
    __syncthreads();

    // log_prob[k] = mean_q (l_pos - log(exp(l_pos) + neg[k]))
    for (int k = wv; k < K_; k += 4) {
        float neg = 0.f;
        #pragma unroll
        for (int j = 0; j < K_; ++j)
            if (j != k) neg += sumE_s[k][j];
        float lp = lpos_s[k][lane];
        float term = lp - logf(expf(lp) + neg);
        #pragma unroll
        for (int off = 32; off > 0; off >>= 1) term += __shfl_down(term, off);
        if (lane == 0) logprob_s[k] = term * (1.0f / (float)Q_);
    }
    __syncthreads();

    if (tid == 0) {
        float lsum = 0.f;
        #pragma unroll
        for (int k = 0; k < K_; ++k)
            if (valid_s[k]) lsum += -logprob_s[k];
        int denom = denom_s;
        per_sample[b] = (denom > 0) ? (lsum / (float)denom) : 0.f;
    }
}

// ---------------------------------------------------------------------------
// Kernel 4: final reduction over B samples.
// ---------------------------------------------------------------------------
__global__ __launch_bounds__(64) void final_kernel(
    const float* __restrict__ per_sample, float* __restrict__ out)
{
    int tid = threadIdx.x;
    float v = (tid < B_) ? per_sample[tid] : 0.f;
    #pragma unroll
    for (int off = 32; off > 0; off >>= 1) v += __shfl_down(v, off);
    if (tid == 0) out[0] = v / (float)B_;
}

// ---------------------------------------------------------------------------
extern "C" void kernel_launch(void* const* d_in, const int* in_sizes, int n_in,
                              void* d_out, int out_size, void* d_ws, size_t ws_size,
                              hipStream_t stream)
{
    const float* res1     = (const float*)d_in[0];
    const float* fea1     = (const float*)d_in[1];
    const float* queues   = (const float*)d_in[2];
    const int*   gt       = (const int*)d_in[3];
    const int*   label_bs = (const int*)d_in[4];
    float* out = (float*)d_out;

    char* ws = (char*)d_ws;
    int*   pred       = (int*)ws;                              // B*HW ints   (1 MB)
    float* sums       = (float*)(ws + (size_t)B_ * HW_ * 4);   // B*K*C floats
    float* counts     = sums + (size_t)B_ * K_ * C_;           // B*K floats
    float* per_sample = counts + B_ * K_;                      // B floats

    pred_kernel<<<B_ * HW_ / 256, 256, 0, stream>>>(res1, gt, label_bs, pred);
    segsum_kernel<<<B_ * C_, 256, 0, stream>>>(fea1, pred, sums, counts);
    loss_kernel<<<B_, 256, 0, stream>>>(sums, counts, queues, per_sample);
    final_kernel<<<1, 64, 0, stream>>>(per_sample, out);
}

// Round 2
// 64.497 us; speedup vs baseline: 1.3156x; 1.3156x over previous
//
#include <hip/hip_runtime.h>
#include <cstddef>

constexpr int B_  = 16;
constexpr int K_  = 5;
constexpr int C_  = 256;
constexpr int HW_ = 128 * 128;
constexpr int Q_  = 64;
constexpr float T_ = 0.2f;

typedef float f4 __attribute__((ext_vector_type(4)));

// ---------------------------------------------------------------------------
// Kernel 1: per-pixel prediction, packed 4 pixels -> 1 uint (bytes).
// pred[b,p] = gt[b,p] if b < label_bs else argmax_k res1[b,k,p] (first max).
// ---------------------------------------------------------------------------
__global__ __launch_bounds__(256) void pred_kernel(
    const float* __restrict__ res1, const int* __restrict__ gt,
    const int* __restrict__ label_bs, unsigned int* __restrict__ predp)
{
    int idx = blockIdx.x * 256 + threadIdx.x;   // 0 .. B*HW/4
    int b  = idx >> 12;                         // / (HW/4)
    int p4 = idx & 4095;
    int lb = label_bs[0];
    unsigned int packed;
    if (b < lb) {
        int4 g = reinterpret_cast<const int4*>(gt + (size_t)b * HW_)[p4];
        packed = (unsigned)(g.x & 0xFF) | ((unsigned)(g.y & 0xFF) << 8)
               | ((unsigned)(g.z & 0xFF) << 16) | ((unsigned)(g.w & 0xFF) << 24);
    } else {
        const float4* r = reinterpret_cast<const float4*>(res1 + (size_t)b * K_ * HW_) + p4;
        float4 best = r[0];
        int a0 = 0, a1 = 0, a2 = 0, a3 = 0;
        #pragma unroll
        for (int k = 1; k < K_; ++k) {
            float4 v = r[(size_t)k * (HW_ / 4)];
            if (v.x > best.x) { best.x = v.x; a0 = k; }   // strict >: first max
            if (v.y > best.y) { best.y = v.y; a1 = k; }
            if (v.z > best.z) { best.z = v.z; a2 = k; }
            if (v.w > best.w) { best.w = v.w; a3 = k; }
        }
        packed = (unsigned)a0 | ((unsigned)a1 << 8) | ((unsigned)a2 << 16) | ((unsigned)a3 << 24);
    }
    predp[idx] = packed;
}

// ---------------------------------------------------------------------------
// Kernel 2: masked segment sums. One block per (b,c); streams fea row with
// non-temporal float4 loads + byte-packed preds; direct unique-owner writes.
// ---------------------------------------------------------------------------
__global__ __launch_bounds__(256) void segsum_kernel(
    const float* __restrict__ fea, const unsigned int* __restrict__ predp,
    float* __restrict__ sums, float* __restrict__ counts)
{
    int bc = blockIdx.x;
    int b = bc >> 8;              // / C_
    int c = bc & (C_ - 1);
    int tid = threadIdx.x;
    const f4* frow = reinterpret_cast<const f4*>(fea + ((size_t)b * C_ + c) * HW_);
    const unsigned int* prow = predp + (size_t)b * (HW_ / 4);

    float acc[K_] = {};
    int   cnt[K_] = {};
    const bool do_count = (c == 0);

    for (int i = tid; i < HW_ / 4; i += 256) {
        f4 v = __builtin_nontemporal_load(frow + i);
        unsigned u = prow[i];
        int k0 = u & 255, k1 = (u >> 8) & 255, k2 = (u >> 16) & 255, k3 = u >> 24;
        #pragma unroll
        for (int k = 0; k < K_; ++k) {
            acc[k] += (k0 == k ? v.x : 0.f)
                    + (k1 == k ? v.y : 0.f)
                    + (k2 == k ? v.z : 0.f)
                    + (k3 == k ? v.w : 0.f);
        }
        if (do_count) {
            #pragma unroll
            for (int k = 0; k < K_; ++k)
                cnt[k] += (k0 == k) + (k1 == k) + (k2 == k) + (k3 == k);
        }
    }

    __shared__ float red[4][K_];
    __shared__ int   redc[4][K_];
    int lane = tid & 63, wv = tid >> 6;
    #pragma unroll
    for (int k = 0; k < K_; ++k) {
        float v = acc[k];
        #pragma unroll
        for (int off = 32; off > 0; off >>= 1) v += __shfl_down(v, off);
        if (lane == 0) red[wv][k] = v;
        if (do_count) {
            int ci = cnt[k];
            #pragma unroll
            for (int off = 32; off > 0; off >>= 1) ci += __shfl_down(ci, off);
            if (lane == 0) redc[wv][k] = ci;
        }
    }
    __syncthreads();
    if (tid < K_) {
        sums[((size_t)b * K_ + tid) * C_ + c] =
            red[0][tid] + red[1][tid] + red[2][tid] + red[3][tid];
        if (do_count)
            counts[b * K_ + tid] =
                (float)(redc[0][tid] + redc[1][tid] + redc[2][tid] + redc[3][tid]);
    }
}

// ---------------------------------------------------------------------------
// Kernel 3: contrastive tail, one block per (b,k): normalize the query key
// (class max(prev,0)), dot against all 5 queue banks, write logprob[b,k].
// ---------------------------------------------------------------------------
__global__ __launch_bounds__(256) void loss_kernel(
    const float* __restrict__ sums, const float* __restrict__ counts,
    const float* __restrict__ queues, float* __restrict__ logprob)
{
    int bk = blockIdx.x;
    int b = bk / K_;
    int k = bk - b * K_;
    int tid = threadIdx.x, lane = tid & 63, wv = tid >> 6;

    __shared__ float key[C_];
    __shared__ float wred[4];
    __shared__ float sumE_s[K_];
    __shared__ float lpos_s[Q_];

    // prev (cummax off-by-one): last present class with index < k
    float cv[K_];
    #pragma unroll
    for (int j = 0; j < K_; ++j) cv[j] = counts[b * K_ + j];
    int prev = -1;
    #pragma unroll
    for (int j = 0; j < K_; ++j)
        if (j < k && cv[j] > 0.0f) prev = j;
    int pk = prev < 0 ? 0 : prev;

    // mean of class pk, L2-normalized over C (thread tid owns channel tid)
    float m = sums[((size_t)b * K_ + pk) * C_ + tid] / fmaxf(cv[pk], 1.0f);
    float s = m * m;
    #pragma unroll
    for (int off = 32; off > 0; off >>= 1) s += __shfl_down(s, off);
    if (lane == 0) wred[wv] = s;
    __syncthreads();
    float nrm = sqrtf(wred[0] + wred[1] + wred[2] + wred[3]);
    key[tid] = m / fmaxf(nrm, 1e-12f);
    __syncthreads();

    // sim[k,j,:] over waves; lanes = q
    for (int j = wv; j < K_; j += 4) {
        const float* qj = queues + (size_t)j * C_ * Q_ + lane;
        float acc = 0.f;
        for (int c = 0; c < C_; ++c)
            acc += key[c] * qj[(size_t)c * Q_];
        acc = acc / T_;
        float e = expf(acc);
        float se = e;
        #pragma unroll
        for (int off = 32; off > 0; off >>= 1) se += __shfl_down(se, off);
        if (lane == 0) sumE_s[j] = se;
        if (j == k) lpos_s[lane] = acc;
    }
    __syncthreads();

    if (wv == 0) {
        float neg = 0.f;
        #pragma unroll
        for (int j = 0; j < K_; ++j)
            if (j != k) neg += sumE_s[j];
        float lp = lpos_s[lane];
        float term = lp - logf(expf(lp) + neg);
        #pragma unroll
        for (int off = 32; off > 0; off >>= 1) term += __shfl_down(term, off);
        if (lane == 0) logprob[bk] = term * (1.0f / (float)Q_);
    }
}

// ---------------------------------------------------------------------------
// Kernel 4: valid/denom masking + reductions. lane b handles sample b.
// ---------------------------------------------------------------------------
__global__ __launch_bounds__(64) void final_kernel(
    const float* __restrict__ counts, const float* __restrict__ logprob,
    float* __restrict__ out)
{
    int tid = threadIdx.x;
    float per = 0.f;
    if (tid < B_) {
        int last = -1, smallest = -1, npres = 0;
        float lsum = 0.f;
        #pragma unroll
        for (int k = 0; k < K_; ++k) {
            bool pres = counts[tid * K_ + k] > 0.0f;
            bool valid = pres && smallest >= 0 && last >= 0;
            if (valid) lsum += -logprob[tid * K_ + k];
            if (pres && smallest < 0) smallest = k;
            if (pres) { ++npres; last = k; }
        }
        int denom = npres - 1;
        per = (denom > 0) ? (lsum / (float)denom) : 0.f;
    }
    #pragma unroll
    for (int off = 32; off > 0; off >>= 1) per += __shfl_down(per, off);
    if (tid == 0) out[0] = per / (float)B_;
}

// ---------------------------------------------------------------------------
extern "C" void kernel_launch(void* const* d_in, const int* in_sizes, int n_in,
                              void* d_out, int out_size, void* d_ws, size_t ws_size,
                              hipStream_t stream)
{
    const float* res1     = (const float*)d_in[0];
    const float* fea1     = (const float*)d_in[1];
    const float* queues   = (const float*)d_in[2];
    const int*   gt       = (const int*)d_in[3];
    const int*   label_bs = (const int*)d_in[4];
    float* out = (float*)d_out;

    char* ws = (char*)d_ws;
    unsigned int* predp = (unsigned int*)ws;                       // B*HW/4 uints (256 KB)
    float* sums    = (float*)(ws + (size_t)B_ * (HW_ / 4) * 4);    // B*K*C floats
    float* counts  = sums + (size_t)B_ * K_ * C_;                  // B*K floats
    float* logprob = counts + B_ * K_;                             // B*K floats

    pred_kernel<<<B_ * HW_ / 4 / 256, 256, 0, stream>>>(res1, gt, label_bs, predp);
    segsum_kernel<<<B_ * C_, 256, 0, stream>>>(fea1, predp, sums, counts);
    loss_kernel<<<B_ * K_, 256, 0, stream>>>(sums, counts, queues, logprob);
    final_kernel<<<1, 64, 0, stream>>>(counts, logprob, out);
}